// Round 9
// baseline (43.371 us; speedup 1.0000x reference)
//
#include <hip/hip_runtime.h>

#define H     128
#define W     128
#define HO    126
#define WO    126
#define NPIX  (HO * WO)          // 15876

// load one 3-row x 6-col group window from LDS (6 ds_reads, const offsets)
__device__ __forceinline__ void ldgrp(float r[3][6], const float* __restrict__ p) {
#pragma unroll
    for (int dr = 0; dr < 3; ++dr) {
        const float4 a = *(const float4*)(p + dr * W);
        const float2 b = *(const float2*)(p + dr * W + 4);
        r[dr][0] = a.x; r[dr][1] = a.y; r[dr][2] = a.z; r[dr][3] = a.w;
        r[dr][4] = b.x; r[dr][5] = b.y;
    }
}

// 4-pixel group math (R8 body)
__device__ __forceinline__ float grp(const float r[3][6], bool full) {
    float cs[6], cq[6], cm[6];
#pragma unroll
    for (int c = 0; c < 6; ++c) {
        cs[c] = r[0][c] + r[1][c] + r[2][c];
        cq[c] = fmaf(r[0][c], r[0][c], fmaf(r[1][c], r[1][c], r[2][c] * r[2][c]));
        cm[c] = fmaxf(r[0][c], fmaxf(r[1][c], r[2][c]));   // -> v_max3
    }

    float bnv[4];
#pragma unroll
    for (int k = 0; k < 4; ++k) {
        const float ctr  = r[1][k + 1];
        const float sum  = cs[k] + cs[k + 1] + cs[k + 2];
        const float ss   = cq[k] + cq[k + 1] + cq[k + 2];
        const float wmax = fmaxf(cm[k], fmaxf(cm[k + 1], cm[k + 2]));

        float d[8];
        d[0] = r[0][k]     - ctr;  d[1] = r[0][k + 1] - ctr;
        d[2] = r[0][k + 2] - ctr;  d[3] = r[1][k]     - ctr;
        d[4] = r[1][k + 2] - ctr;  d[5] = r[2][k]     - ctr;
        d[6] = r[2][k + 1] - ctr;  d[7] = r[2][k + 2] - ctr;

        const float sad = ((fabsf(d[0]) + fabsf(d[1])) + (fabsf(d[2]) + fabsf(d[3])))
                        + ((fabsf(d[4]) + fabsf(d[5])) + (fabsf(d[6]) + fabsf(d[7])));
        const float thr = sad * (1.f / 9.f);

        int b0 = (sad <= 0.f) ? 1 : 0;   // center tap: 0 >= thr
        b0 += d[0] >= thr;
        b0 += d[1] >= thr;
        b0 += d[2] >= thr;
        b0 += d[3] >= thr;
        int b1 = d[4] >= thr;
        b1 += d[5] >= thr;
        b1 += d[6] >= thr;
        b1 += d[7] >= thr;
        const float bv = (float)(b0 + b1);

        const float var9 = fmaf(sum, -sum, 9.f * ss);                // 81*var
        const float sd9  = __builtin_amdgcn_sqrtf(fmaxf(var9, 0.f)); // 9*std
        const float nf   = fmaf(sum, -1.f / 2295.f, bv * (1.f / 255.f));
        bnv[k] = fmaf(nf, fmaf(sd9, 1.f / 9.f, -wmax), wmax);
    }

    float gs = bnv[0] + bnv[1];
    gs += full ? (bnv[2] + bnv[3]) : 0.f;   // xq==31: px 2,3 out of range
    return gs;
}

// One block per plane, 1024 threads, single dispatch.
// Groups: 4032 = 126 rows x 32; thread t owns groups t, t+1024, t+2048, t+3072.
// Group g's LDS float base is exactly 4g (128*y + 4*xq == 4g) -> one addr reg,
// all 24 ds_reads use constant offsets. RA/RB double-buffer pipelines loads.
__global__ __launch_bounds__(1024) void bp_kernel(const float* __restrict__ x,
                                                  float* __restrict__ out) {
    __shared__ float tile[H * W + 8];   // +8: xq==31 garbage float2 stays in LDS
    __shared__ float wred[16];

    const int t     = threadIdx.x;
    const int plane = blockIdx.x;

    // ---- stage full plane: 4 coalesced float4 per thread ----
    const float4* s4 = (const float4*)(x + (size_t)plane * (H * W));
    float4* t4 = (float4*)tile;
#pragma unroll
    for (int i = 0; i < 4; ++i)
        t4[t + 1024 * i] = s4[t + 1024 * i];
    __syncthreads();

    const bool full = (t & 31) != 31;       // invariant: stride 1024 % 32 == 0
    const float* p0 = &tile[4 * t];

    float RA[3][6], RB[3][6];
    float acc = 0.f;

    ldgrp(RA, p0);                            // it0
    ldgrp(RB, p0 + 4096);                     // it1
    acc += grp(RA, full);                     // it0
    ldgrp(RA, p0 + 8192);                     // it2
    acc += grp(RB, full);                     // it1
    const int gp = min(t + 3072, 4031);       // clamp keeps reads in-tile
    ldgrp(RB, &tile[4 * gp]);                 // it3 (t>=960: dummy, discarded)
    acc += grp(RA, full);                     // it2
    if (t < 960)                              // 960 = 15*64: wave-aligned, no divergence
        acc += grp(RB, full);                 // it3

    // ---- reduction: 16 waves -> 16 partials -> wave 0 ----
#pragma unroll
    for (int off = 32; off > 0; off >>= 1)
        acc += __shfl_down(acc, off, 64);
    if ((t & 63) == 0) wred[t >> 6] = acc;
    __syncthreads();
    if (t < 64) {
        float v = (t < 16) ? wred[t] : 0.f;
#pragma unroll
        for (int off = 8; off > 0; off >>= 1)
            v += __shfl_down(v, off, 64);
        if (t == 0) out[plane] = v * (1.f / NPIX);
    }
}

extern "C" void kernel_launch(void* const* d_in, const int* in_sizes, int n_in,
                              void* d_out, int out_size, void* d_ws, size_t ws_size,
                              hipStream_t stream) {
    const float* x = (const float*)d_in[0];
    float* out = (float*)d_out;
    bp_kernel<<<dim3(16 * 64), dim3(1024), 0, stream>>>(x, out);
}